// Round 3
// baseline (303.189 us; speedup 1.0000x reference)
//
#include <hip/hip_runtime.h>

#define N_NODES 50000
#define N_EDGES 640000
#define CH 128
#define NTILES 1563   // gather tiles of 32 rows
#define IDS_CAP 768   // LDS CSR slice cap: Poisson(410), 768 = +17.7 sigma

typedef __bf16 bf16_t;
typedef bf16_t bf16x8 __attribute__((ext_vector_type(8)));
typedef float f32x4 __attribute__((ext_vector_type(4)));

__device__ __forceinline__ ushort f2bf(float f) {
  union { float f; unsigned u; } v; v.f = f;
  unsigned r = v.u + 0x7FFFu + ((v.u >> 16) & 1u);   // RNE
  return (ushort)(r >> 16);
}
__device__ __forceinline__ float bflo(unsigned u) {
  union { unsigned u; float f; } v; v.u = u << 16; return v.f;
}
__device__ __forceinline__ float bfhi(unsigned u) {
  union { unsigned u; float f; } v; v.u = u & 0xFFFF0000u; return v.f;
}
__device__ __forceinline__ unsigned pack2(float lo, float hi) {
  return (unsigned)f2bf(lo) | ((unsigned)f2bf(hi) << 16);
}
__device__ __forceinline__ void addrow(float* acc, uint4 v) {
  acc[0] += bflo(v.x); acc[1] += bfhi(v.x);
  acc[2] += bflo(v.y); acc[3] += bfhi(v.y);
  acc[4] += bflo(v.z); acc[5] += bfhi(v.z);
  acc[6] += bflo(v.w); acc[7] += bfhi(v.w);
}

// ws layout (bytes), all 16B-aligned:
//   ptr  : [0, 200016)            50001 int  (CSR row pointers)
//   cur  : [200016, 400016)       50000 int  (scatter cursors)
//   cnt  : [400032, 600032)       50000 int  (degree histogram)
//   colw : [600032, 1880032)      640000 ushort (CSR cols; node id < 65536)
//   Wb   : [1880032, 1912800)     128x128 bf16
//   xb   : [1912800, 14712800)    N_NODES*CH bf16
// total ~14.7 MB. CSR replaces the poison-sentinel bin array: writes are
// dense runs (~26 B/row) in a 1.28 MB L2-resident array, and fused reads
// exactly the valid records (no poison scan, no capacity caps).

__global__ __launch_bounds__(256) void zero_cnt(int4* __restrict__ cnt4) {
  int i = blockIdx.x * 256 + threadIdx.x;
  if (i < N_NODES / 4) cnt4[i] = make_int4(0, 0, 0, 0);
}

// Blocks [0,625): degree histogram (4 edges/thread, 640000 = 625*1024).
// Blocks [625,3750): x -> bf16. Block 3750: W -> bf16.
__global__ __launch_bounds__(256) void prep(const int* __restrict__ row,
                                            int* __restrict__ cnt,
                                            const float4* __restrict__ x4,
                                            uint4* __restrict__ xb4,
                                            const float4* __restrict__ W4,
                                            uint4* __restrict__ Wb4) {
  int bid = blockIdx.x;
  int tid = threadIdx.x;
  if (bid < 625) {
    int base = bid * 1024 + tid * 4;
    int4 r4 = *(const int4*)(row + base);
    atomicAdd(&cnt[r4.x], 1);
    atomicAdd(&cnt[r4.y], 1);
    atomicAdd(&cnt[r4.z], 1);
    atomicAdd(&cnt[r4.w], 1);
  } else if (bid < 3750) {
    int i = (bid - 625) * 256 + tid;        // 800000 threads exactly
    float4 a = x4[i * 2], b = x4[i * 2 + 1];
    uint4 o;
    o.x = pack2(a.x, a.y); o.y = pack2(a.z, a.w);
    o.z = pack2(b.x, b.y); o.w = pack2(b.z, b.w);
    xb4[i] = o;
  } else {
    for (int i = tid; i < 2048; i += 256) {
      float4 c = W4[i * 2], d = W4[i * 2 + 1];
      uint4 w;
      w.x = pack2(c.x, c.y); w.y = pack2(c.z, c.w);
      w.z = pack2(d.x, d.y); w.w = pack2(d.z, d.w);
      Wb4[i] = w;
    }
  }
}

// Single-block exclusive prefix scan over cnt -> ptr (and cur copy).
// 1024 threads x chunks of 49 (1024*49 = 50176 >= 50000).
__global__ __launch_bounds__(1024) void scan_k(const int* __restrict__ cnt,
                                               int* __restrict__ ptr,
                                               int* __restrict__ cur) {
  __shared__ int ls[1024];
  int t = threadIdx.x;
  int base = t * 49;
  int s = 0;
  for (int k = 0; k < 49; ++k) {
    int i = base + k;
    if (i < N_NODES) s += cnt[i];
  }
  ls[t] = s;
  __syncthreads();
  for (int off = 1; off < 1024; off <<= 1) {   // Hillis-Steele inclusive
    int v = (t >= off) ? ls[t - off] : 0;
    __syncthreads();
    ls[t] += v;
    __syncthreads();
  }
  int run = (t > 0) ? ls[t - 1] : 0;           // exclusive base for my chunk
  for (int k = 0; k < 49; ++k) {
    int i = base + k;
    if (i < N_NODES) {
      ptr[i] = run;
      cur[i] = run;
      run += cnt[i];
    }
  }
  if (t == 1023) ptr[N_NODES] = ls[1023];      // = N_EDGES
}

// CSR scatter: pos = cur[row]++, colw[pos] = col. Dense ~26 B runs per row.
__global__ __launch_bounds__(256) void scatter(const int* __restrict__ row,
                                               const int* __restrict__ col,
                                               int* __restrict__ cur,
                                               ushort* __restrict__ colw) {
  int base = blockIdx.x * 1024 + threadIdx.x * 4;
  int4 r4 = *(const int4*)(row + base);
  int4 c4 = *(const int4*)(col + base);
  int p0 = atomicAdd(&cur[r4.x], 1); colw[p0] = (ushort)c4.x;
  int p1 = atomicAdd(&cur[r4.y], 1); colw[p1] = (ushort)c4.y;
  int p2 = atomicAdd(&cur[r4.z], 1); colw[p2] = (ushort)c4.z;
  int p3 = atomicAdd(&cur[r4.w], 1); colw[p3] = (ushort)c4.w;
}

// Fused Stage A (CSR slice -> LDS, exact degrees) + Stage B (gather+
// normalize+residual) + GEMM (swapped-operand MFMA, hT XOR-swizzled).
// 256 threads = 4 waves per 32-row tile.
__global__ __launch_bounds__(256) void fused(const uint4* __restrict__ xb4,
                                             const int* __restrict__ ptr,
                                             const ushort* __restrict__ colw,
                                             const uint4* __restrict__ Wb4,
                                             const float4* __restrict__ bias4,
                                             float4* __restrict__ out4) {
  __shared__ ushort hT[32 * CH];       // 8192 B, uint4-slot s stored at s^(r&15)
  __shared__ ushort idsL[IDS_CAP];     // 1536 B, block's contiguous CSR slice
  __shared__ int lp[33];
  int tid = threadIdx.x;
  int g = blockIdx.x;
  int m0 = g * 32;

  // ---- Stage A: row pointers + contiguous CSR slice into LDS ----
  if (tid < 33) {
    int idx = m0 + tid;
    if (idx > N_NODES) idx = N_NODES;  // tail tile: rows >= N_NODES get deg 0
    lp[tid] = ptr[idx];
  }
  __syncthreads();
  int cbase = lp[0];
  int total = lp[32] - cbase;
  if (total > IDS_CAP) total = IDS_CAP;   // statistically impossible
  for (int i = tid; i < total; i += 256) idsL[i] = colw[cbase + i];
  __syncthreads();

  // ---- Stage B: gather + normalize + residual -> hT (bf16) ----
  int wv = tid >> 6;          // 0..3
  int lane = tid & 63;
  int q = lane & 15;          // uint4 chunk within a 128-ch bf16 row
  int grp = lane >> 4;        // 0..3
#pragma unroll
  for (int t = 0; t < 2; ++t) {
    int r = wv * 8 + t * 4 + grp;
    int node = m0 + r;
    int deg = lp[r + 1] - lp[r];
    const ushort* arow = idsL + (lp[r] - cbase);
    float acc[8] = {0.f, 0.f, 0.f, 0.f, 0.f, 0.f, 0.f, 0.f};
    int e = 0;
    for (; e + 3 < deg; e += 4) {
      int n0 = arow[e], n1 = arow[e + 1], n2 = arow[e + 2], n3 = arow[e + 3];
      uint4 v0 = xb4[n0 * 16 + q];
      uint4 v1 = xb4[n1 * 16 + q];
      uint4 v2 = xb4[n2 * 16 + q];
      uint4 v3 = xb4[n3 * 16 + q];
      addrow(acc, v0);
      addrow(acc, v1);
      addrow(acc, v2);
      addrow(acc, v3);
    }
    for (; e < deg; ++e) {
      int nb = arow[e];
      uint4 v = xb4[nb * 16 + q];
      addrow(acc, v);
    }
    uint4 o = make_uint4(0, 0, 0, 0);
    if (node < N_NODES) {
      float s = 1.0f / fmaxf((float)deg, 1.0f);
      uint4 xi = xb4[node * 16 + q];
      o.x = pack2(bflo(xi.x) + acc[0] * s, bfhi(xi.x) + acc[1] * s);
      o.y = pack2(bflo(xi.y) + acc[2] * s, bfhi(xi.y) + acc[3] * s);
      o.z = pack2(bflo(xi.z) + acc[4] * s, bfhi(xi.z) + acc[5] * s);
      o.w = pack2(bflo(xi.w) + acc[6] * s, bfhi(xi.w) + acc[7] * s);
    }
    *(uint4*)&hT[r * CH + ((q ^ (r & 15)) << 3)] = o;
  }
  __syncthreads();

  // ---- GEMM: swapped-operand MFMA, D[n=qq*4+r][m=lane&15] -> float4 stores
  // 2 m-tiles x 8 n-tiles over 4 waves: wv -> mt = wv&1, n-tiles (wv>>1)*4..+3
  // hT uint4-slot s of row r lives at s^(r&15): reads spread across bank quads.
  int qq = grp;
  int mt = wv & 1;
  int nbase = (wv >> 1) * 4;
  const ushort* hbase = &hT[(mt * 16 + q) * CH];   // row rr_: rr_&15 == q
  bf16x8 hb0 = *(const bf16x8*)(hbase + (((qq + 0) ^ q) << 3));
  bf16x8 hb1 = *(const bf16x8*)(hbase + (((qq + 4) ^ q) << 3));
  bf16x8 hb2 = *(const bf16x8*)(hbase + (((qq + 8) ^ q) << 3));
  bf16x8 hb3 = *(const bf16x8*)(hbase + (((qq + 12) ^ q) << 3));
  int m = m0 + mt * 16 + q;
#pragma unroll
  for (int i = 0; i < 4; ++i) {
    int nt = nbase + i;
    const uint4* wr = Wb4 + (nt * 16 + q) * 16 + qq;   // k-step 32 bf16 = 4 uint4
    bf16x8 w0 = __builtin_bit_cast(bf16x8, wr[0]);
    bf16x8 w1 = __builtin_bit_cast(bf16x8, wr[4]);
    bf16x8 w2 = __builtin_bit_cast(bf16x8, wr[8]);
    bf16x8 w3 = __builtin_bit_cast(bf16x8, wr[12]);
    f32x4 acc = {0.f, 0.f, 0.f, 0.f};
    acc = __builtin_amdgcn_mfma_f32_16x16x32_bf16(w0, hb0, acc, 0, 0, 0);
    acc = __builtin_amdgcn_mfma_f32_16x16x32_bf16(w1, hb1, acc, 0, 0, 0);
    acc = __builtin_amdgcn_mfma_f32_16x16x32_bf16(w2, hb2, acc, 0, 0, 0);
    acc = __builtin_amdgcn_mfma_f32_16x16x32_bf16(w3, hb3, acc, 0, 0, 0);
    if (m < N_NODES) {
      float4 bv = bias4[nt * 4 + qq];
      f32x4 o;
      o.x = acc[0] + bv.x;
      o.y = acc[1] + bv.y;
      o.z = acc[2] + bv.z;
      o.w = acc[3] + bv.w;
      __builtin_nontemporal_store(o, (f32x4*)(out4 + (size_t)m * 32 + nt * 4 + qq));
    }
  }
}

extern "C" void kernel_launch(void* const* d_in, const int* in_sizes, int n_in,
                              void* d_out, int out_size, void* d_ws, size_t ws_size,
                              hipStream_t stream) {
  const float* x  = (const float*)d_in[0];
  const int*   ei = (const int*)d_in[1];    // [2, N_EDGES]: row then col
  const float* W  = (const float*)d_in[2];
  const float* bb = (const float*)d_in[3];

  char* ws = (char*)d_ws;
  int*    ptr  = (int*)ws;
  int*    cur  = (int*)(ws + 200016);
  int*    cnt  = (int*)(ws + 400032);
  ushort* colw = (ushort*)(ws + 600032);
  uint4*  Wb4  = (uint4*)(ws + 1880032);
  uint4*  xb4  = (uint4*)(ws + 1912800);

  zero_cnt<<<49, 256, 0, stream>>>((int4*)cnt);
  prep<<<3751, 256, 0, stream>>>(ei, cnt, (const float4*)x, xb4,
                                 (const float4*)W, Wb4);
  scan_k<<<1, 1024, 0, stream>>>(cnt, ptr, cur);
  scatter<<<625, 256, 0, stream>>>(ei, ei + N_EDGES, cur, colw);
  fused<<<NTILES, 256, 0, stream>>>(xb4, ptr, colw, Wb4,
                                    (const float4*)bb, (float4*)d_out);
}

// Round 4
// 133.693 us; speedup vs baseline: 2.2678x; 2.2678x over previous
//
#include <hip/hip_runtime.h>

#define N_NODES 50000
#define N_EDGES 640000
#define CH 128
#define NBINS 1563    // bins of 32 rows (row >> 5); one bin per fused block
#define NTILES 1563   // gather tiles of 32 rows == NBINS
#define FILLB 64      // fill blocks
#define EPB 10000     // edges per fill block (64*10000 = 640000)
#define OBW (NBINS + 1)   // obo row width (offsets + sentinel)
#define CAPR 48       // per-row LDS slot capacity; P(deg>48) ~ 1e-15

typedef __bf16 bf16_t;
typedef bf16_t bf16x8 __attribute__((ext_vector_type(8)));
typedef float f32x4 __attribute__((ext_vector_type(4)));

__device__ __forceinline__ ushort f2bf(float f) {
  union { float f; unsigned u; } v; v.f = f;
  unsigned r = v.u + 0x7FFFu + ((v.u >> 16) & 1u);   // RNE
  return (ushort)(r >> 16);
}
__device__ __forceinline__ float bflo(unsigned u) {
  union { unsigned u; float f; } v; v.u = u << 16; return v.f;
}
__device__ __forceinline__ float bfhi(unsigned u) {
  union { unsigned u; float f; } v; v.u = u & 0xFFFF0000u; return v.f;
}
__device__ __forceinline__ unsigned pack2(float lo, float hi) {
  return (unsigned)f2bf(lo) | ((unsigned)f2bf(hi) << 16);
}
__device__ __forceinline__ void addrow(float* acc, uint4 v) {
  acc[0] += bflo(v.x); acc[1] += bfhi(v.x);
  acc[2] += bflo(v.y); acc[3] += bfhi(v.y);
  acc[4] += bflo(v.z); acc[5] += bfhi(v.z);
  acc[6] += bflo(v.w); acc[7] += bfhi(v.w);
}

// ws layout (bytes), 16B-aligned:
//   binRec : [0, 2560000)           640000 uint, block i's records DENSE at
//            [i*EPB, (i+1)*EPB), grouped by bin via in-block LDS scan.
//            rec = (lrow5 << 16) | col16. No poison, no capacity caps.
//   obo    : [2560000, 2760192)     64 x 1564 ushort: obo[i][g] = offset of
//            bin g within block i's region; obo[i][NBINS] = EPB.
//   Wb     : [2760192, 2792960)     128x128 bf16
//   xb     : [2792960, 15592960)    N_NODES*CH bf16
// All binning is LDS-local (histogram/scan/place) -> zero global atomics,
// coalesced record dump, and fused reads exactly the valid records.

// Blocks [0,64): LDS-binning, 10000 edges/block.
// Blocks [64,3189): x -> bf16. Block 3189: W -> bf16.
__global__ __launch_bounds__(256) void fill_conv(const int* __restrict__ row,
                                                 const int* __restrict__ col,
                                                 unsigned* __restrict__ binRec,
                                                 ushort* __restrict__ obo,
                                                 const float4* __restrict__ x4,
                                                 uint4* __restrict__ xb4,
                                                 const float4* __restrict__ W4,
                                                 uint4* __restrict__ Wb4) {
  __shared__ int cnt[NBINS];                      // hist, then offsets
  __shared__ int parts[256];
  __shared__ __align__(16) unsigned recbuf[EPB];  // 40000 B
  int bid = blockIdx.x;
  int tid = threadIdx.x;
  if (bid < FILLB) {
    for (int i = tid; i < NBINS; i += 256) cnt[i] = 0;
    __syncthreads();
    int base = bid * EPB;
    // pass 1: count + per-record rank within (block, bin); pk = bi<<8 | rk
    unsigned pk[40];
#pragma unroll
    for (int k = 0; k < 40; ++k) {
      int idx = tid + k * 256;
      pk[k] = 0xFFFFFFFFu;
      if (idx < EPB) {
        int rr = row[base + idx];
        int bi = rr >> 5;
        int rk = atomicAdd(&cnt[bi], 1);          // LDS atomic: cheap
        pk[k] = ((unsigned)bi << 8) | (unsigned)rk;
      }
    }
    __syncthreads();
    // in-block exclusive scan of cnt (chunks of 7 per thread, 256*7 >= NBINS)
    int c7[7];
    int s = 0;
#pragma unroll
    for (int k = 0; k < 7; ++k) {
      int i = tid * 7 + k;
      int c = (i < NBINS) ? cnt[i] : 0;
      c7[k] = c; s += c;
    }
    parts[tid] = s;
    __syncthreads();
    for (int off = 1; off < 256; off <<= 1) {     // Hillis-Steele inclusive
      int v = (tid >= off) ? parts[tid - off] : 0;
      __syncthreads();
      parts[tid] += v;
      __syncthreads();
    }
    int run = (tid > 0) ? parts[tid - 1] : 0;
    ushort* orow = obo + bid * OBW;
#pragma unroll
    for (int k = 0; k < 7; ++k) {
      int i = tid * 7 + k;
      if (i < NBINS) {
        orow[i] = (ushort)run;
        cnt[i] = run;                             // cnt becomes offset
        run += c7[k];
      }
    }
    if (tid == 0) orow[NBINS] = (ushort)EPB;
    __syncthreads();
    // pass 2: place records into LDS at scanned positions
#pragma unroll
    for (int k = 0; k < 40; ++k) {
      int idx = tid + k * 256;
      if (idx < EPB) {
        unsigned p = pk[k];
        int bi = (int)(p >> 8);
        int rk = (int)(p & 255u);
        int rr = row[base + idx];
        int cc = col[base + idx];
        recbuf[cnt[bi] + rk] = ((unsigned)(rr & 31) << 16) | (unsigned)cc;
      }
    }
    __syncthreads();
    // coalesced dump: 2500 uint4
    uint4* gb4 = (uint4*)(binRec + base);
    const uint4* rb4 = (const uint4*)recbuf;
    for (int j = tid; j < EPB / 4; j += 256) gb4[j] = rb4[j];
  } else if (bid < FILLB + 3125) {
    int i = (bid - FILLB) * 256 + tid;            // 800000 threads exactly
    float4 a = x4[i * 2], b = x4[i * 2 + 1];
    uint4 o;
    o.x = pack2(a.x, a.y); o.y = pack2(a.z, a.w);
    o.z = pack2(b.x, b.y); o.w = pack2(b.z, b.w);
    xb4[i] = o;
  } else {
    for (int i = tid; i < 2048; i += 256) {
      float4 c = W4[i * 2], d = W4[i * 2 + 1];
      uint4 w;
      w.x = pack2(c.x, c.y); w.y = pack2(c.z, c.w);
      w.z = pack2(d.x, d.y); w.w = pack2(d.z, d.w);
      Wb4[i] = w;
    }
  }
}

// Fused Stage A (64 dense record runs -> per-row LDS lists) + Stage B
// (gather+normalize+residual, 512 threads, ONE row per 16-lane group,
// 8-wide unrolled gather) + GEMM (swapped-operand MFMA, hT XOR-swizzled,
// 8 waves x 2 n-tiles). One 32-row tile per block.
__global__ __launch_bounds__(512) void fused(const uint4* __restrict__ xb4,
                                             const unsigned* __restrict__ binRec,
                                             const ushort* __restrict__ obo,
                                             const uint4* __restrict__ Wb4,
                                             const float4* __restrict__ bias4,
                                             float4* __restrict__ out4) {
  __shared__ ushort hT[32 * CH];                   // 8192 B, slot s at s^(r&15)
  __shared__ __align__(16) ushort colL[32 * CAPR]; // 3072 B
  __shared__ int rowcnt[32];
  int tid = threadIdx.x;
  int g = blockIdx.x;
  int m0 = g * 32;

  // ---- Stage A: walk 64 dense runs (4 threads per run) ----
  if (tid < 32) rowcnt[tid] = 0;
  __syncthreads();
  if (tid < 256) {
    int i = tid >> 2, sub = tid & 3;
    const ushort* orow = obo + i * OBW + g;
    int o0 = orow[0], o1 = orow[1];
    const unsigned* rbase = binRec + i * EPB;
    for (int p = o0 + sub; p < o1; p += 4) {
      unsigned rec = rbase[p];
      int lr = (int)(rec >> 16);
      int pp = atomicAdd(&rowcnt[lr], 1);
      if (pp < CAPR) colL[lr * CAPR + pp] = (ushort)(rec & 0xFFFFu);
    }
  }
  __syncthreads();

  // ---- Stage B: gather + normalize + residual -> hT (bf16) ----
  int wv = tid >> 6;          // 0..7
  int lane = tid & 63;
  int q = lane & 15;          // uint4 chunk within a 128-ch bf16 row
  int grp = lane >> 4;        // 0..3
  int r = wv * 4 + grp;       // 0..31, single pass
  int node = m0 + r;
  int deg = rowcnt[r];
  int degc = deg < CAPR ? deg : CAPR;
  const ushort* arow = colL + r * CAPR;
  int nc = node < N_NODES ? node : 0;
  uint4 xi = xb4[nc * 16 + q];           // residual, issued before the loop
  float acc[8] = {0.f, 0.f, 0.f, 0.f, 0.f, 0.f, 0.f, 0.f};
  int e = 0;
  for (; e + 7 < degc; e += 8) {         // 8 independent loads in flight
    uint4 ids = *(const uint4*)(arow + e);
    int n0 = ids.x & 0xFFFF, n1 = ids.x >> 16;
    int n2 = ids.y & 0xFFFF, n3 = ids.y >> 16;
    int n4 = ids.z & 0xFFFF, n5 = ids.z >> 16;
    int n6 = ids.w & 0xFFFF, n7 = ids.w >> 16;
    uint4 v0 = xb4[n0 * 16 + q];
    uint4 v1 = xb4[n1 * 16 + q];
    uint4 v2 = xb4[n2 * 16 + q];
    uint4 v3 = xb4[n3 * 16 + q];
    uint4 v4 = xb4[n4 * 16 + q];
    uint4 v5 = xb4[n5 * 16 + q];
    uint4 v6 = xb4[n6 * 16 + q];
    uint4 v7 = xb4[n7 * 16 + q];
    addrow(acc, v0); addrow(acc, v1); addrow(acc, v2); addrow(acc, v3);
    addrow(acc, v4); addrow(acc, v5); addrow(acc, v6); addrow(acc, v7);
  }
  if (e + 3 < degc) {
    uint2 ids = *(const uint2*)(arow + e);
    int n0 = ids.x & 0xFFFF, n1 = ids.x >> 16;
    int n2 = ids.y & 0xFFFF, n3 = ids.y >> 16;
    uint4 v0 = xb4[n0 * 16 + q];
    uint4 v1 = xb4[n1 * 16 + q];
    uint4 v2 = xb4[n2 * 16 + q];
    uint4 v3 = xb4[n3 * 16 + q];
    addrow(acc, v0); addrow(acc, v1); addrow(acc, v2); addrow(acc, v3);
    e += 4;
  }
  for (; e < degc; ++e) {
    uint4 v = xb4[(int)arow[e] * 16 + q];
    addrow(acc, v);
  }
  uint4 o = make_uint4(0, 0, 0, 0);
  if (node < N_NODES) {
    float s = 1.0f / fmaxf((float)deg, 1.0f);
    o.x = pack2(bflo(xi.x) + acc[0] * s, bfhi(xi.x) + acc[1] * s);
    o.y = pack2(bflo(xi.y) + acc[2] * s, bfhi(xi.y) + acc[3] * s);
    o.z = pack2(bflo(xi.z) + acc[4] * s, bfhi(xi.z) + acc[5] * s);
    o.w = pack2(bflo(xi.w) + acc[6] * s, bfhi(xi.w) + acc[7] * s);
  }
  *(uint4*)&hT[r * CH + ((q ^ (r & 15)) << 3)] = o;
  __syncthreads();

  // ---- GEMM: swapped-operand MFMA (proven mapping), 8 waves x 2 n-tiles.
  // hT uint4-slot s of row r lives at s^(r&15): conflict-free fragment reads.
  int qq = grp;
  int mt = wv & 1;
  int nbase = (wv >> 1) * 2;
  const ushort* hbase = &hT[(mt * 16 + q) * CH];   // row rr_: rr_&15 == q
  bf16x8 hb0 = *(const bf16x8*)(hbase + (((qq + 0) ^ q) << 3));
  bf16x8 hb1 = *(const bf16x8*)(hbase + (((qq + 4) ^ q) << 3));
  bf16x8 hb2 = *(const bf16x8*)(hbase + (((qq + 8) ^ q) << 3));
  bf16x8 hb3 = *(const bf16x8*)(hbase + (((qq + 12) ^ q) << 3));
  int m = m0 + mt * 16 + q;
#pragma unroll
  for (int i = 0; i < 2; ++i) {
    int nt = nbase + i;
    const uint4* wr = Wb4 + (nt * 16 + q) * 16 + qq;   // k-step 32 bf16 = 4 uint4
    bf16x8 w0 = __builtin_bit_cast(bf16x8, wr[0]);
    bf16x8 w1 = __builtin_bit_cast(bf16x8, wr[4]);
    bf16x8 w2 = __builtin_bit_cast(bf16x8, wr[8]);
    bf16x8 w3 = __builtin_bit_cast(bf16x8, wr[12]);
    f32x4 acc2 = {0.f, 0.f, 0.f, 0.f};
    acc2 = __builtin_amdgcn_mfma_f32_16x16x32_bf16(w0, hb0, acc2, 0, 0, 0);
    acc2 = __builtin_amdgcn_mfma_f32_16x16x32_bf16(w1, hb1, acc2, 0, 0, 0);
    acc2 = __builtin_amdgcn_mfma_f32_16x16x32_bf16(w2, hb2, acc2, 0, 0, 0);
    acc2 = __builtin_amdgcn_mfma_f32_16x16x32_bf16(w3, hb3, acc2, 0, 0, 0);
    if (m < N_NODES) {
      float4 bv = bias4[nt * 4 + qq];
      f32x4 ov;
      ov.x = acc2[0] + bv.x;
      ov.y = acc2[1] + bv.y;
      ov.z = acc2[2] + bv.z;
      ov.w = acc2[3] + bv.w;
      __builtin_nontemporal_store(ov, (f32x4*)(out4 + (size_t)m * 32 + nt * 4 + qq));
    }
  }
}

extern "C" void kernel_launch(void* const* d_in, const int* in_sizes, int n_in,
                              void* d_out, int out_size, void* d_ws, size_t ws_size,
                              hipStream_t stream) {
  const float* x  = (const float*)d_in[0];
  const int*   ei = (const int*)d_in[1];    // [2, N_EDGES]: row then col
  const float* W  = (const float*)d_in[2];
  const float* bb = (const float*)d_in[3];

  char* ws = (char*)d_ws;
  unsigned* binRec = (unsigned*)ws;
  ushort*   obo    = (ushort*)(ws + 2560000);
  uint4*    Wb4    = (uint4*)(ws + 2760192);
  uint4*    xb4    = (uint4*)(ws + 2792960);

  fill_conv<<<FILLB + 3125 + 1, 256, 0, stream>>>(ei, ei + N_EDGES, binRec, obo,
                                                  (const float4*)x, xb4,
                                                  (const float4*)W, Wb4);
  fused<<<NTILES, 512, 0, stream>>>(xb4, binRec, obo, Wb4,
                                    (const float4*)bb, (float4*)d_out);
}

// Round 5
// 131.766 us; speedup vs baseline: 2.3010x; 1.0146x over previous
//
#include <hip/hip_runtime.h>

#define N_NODES 50000
#define N_EDGES 640000
#define CH 128
#define NBINS 1563    // bins of 32 rows (row >> 5); one bin per fused block
#define NTILES 1563   // gather tiles of 32 rows == NBINS
#define FILLB 128     // fill blocks
#define EPB 5000      // edges per fill block (128*5000 = 640000)
#define OBW (NBINS + 1)   // obo row width (offsets + sentinel)
#define CAPR 48       // per-row LDS slot capacity; P(deg>48) ~ 1e-15

typedef __bf16 bf16_t;
typedef bf16_t bf16x8 __attribute__((ext_vector_type(8)));
typedef float f32x4 __attribute__((ext_vector_type(4)));

__device__ __forceinline__ ushort f2bf(float f) {
  union { float f; unsigned u; } v; v.f = f;
  unsigned r = v.u + 0x7FFFu + ((v.u >> 16) & 1u);   // RNE
  return (ushort)(r >> 16);
}
__device__ __forceinline__ float bflo(unsigned u) {
  union { unsigned u; float f; } v; v.u = u << 16; return v.f;
}
__device__ __forceinline__ float bfhi(unsigned u) {
  union { unsigned u; float f; } v; v.u = u & 0xFFFF0000u; return v.f;
}
__device__ __forceinline__ unsigned pack2(float lo, float hi) {
  return (unsigned)f2bf(lo) | ((unsigned)f2bf(hi) << 16);
}
__device__ __forceinline__ void addrow(float* acc, uint4 v) {
  acc[0] += bflo(v.x); acc[1] += bfhi(v.x);
  acc[2] += bflo(v.y); acc[3] += bfhi(v.y);
  acc[4] += bflo(v.z); acc[5] += bfhi(v.z);
  acc[6] += bflo(v.w); acc[7] += bfhi(v.w);
}

// ws layout (bytes), 16B-aligned:
//   binRec : [0, 2560000)           640000 uint, block i's records DENSE at
//            [i*EPB, (i+1)*EPB), grouped by bin via in-block LDS scan.
//            rec = (lrow5 << 16) | col16.
//   obo    : [2560000, 2960384)     128 x 1564 ushort: obo[i][g] = offset of
//            bin g within block i's region; obo[i][NBINS] = EPB.
//   Wb     : [2960384, 2993152)     128x128 bf16
//   xb     : [2993152, 15793152)    N_NODES*CH bf16
// Binning is LDS-local (histogram/scan/place): zero global atomics, all
// row/col data staged in REGISTERS once (no pass-2 reload), coalesced dump.

// Blocks [0,128): LDS-binning, 5000 edges/block.
// Blocks [128,3253): x -> bf16. Block 3253: W -> bf16.
__global__ __launch_bounds__(256) void fill_conv(const int* __restrict__ row,
                                                 const int* __restrict__ col,
                                                 unsigned* __restrict__ binRec,
                                                 ushort* __restrict__ obo,
                                                 const float4* __restrict__ x4,
                                                 uint4* __restrict__ xb4,
                                                 const float4* __restrict__ W4,
                                                 uint4* __restrict__ Wb4) {
  __shared__ int cnt[NBINS];                      // 6252 B: hist, then offsets
  __shared__ int parts[256];
  __shared__ __align__(16) unsigned recbuf[EPB];  // 20000 B
  int bid = blockIdx.x;
  int tid = threadIdx.x;
  if (bid < FILLB) {
    for (int i = tid; i < NBINS; i += 256) cnt[i] = 0;
    __syncthreads();
    int base = bid * EPB;
    // stage ALL edge data into registers: 10 independent int4 loads in flight
    int4 r4s[5], c4s[5];
    bool val[5];
#pragma unroll
    for (int b = 0; b < 5; ++b) {
      int idx4 = b * 1024 + tid * 4;
      val[b] = idx4 < EPB;                        // EPB%4==0: all-or-nothing
      if (val[b]) {
        r4s[b] = *(const int4*)(row + base + idx4);
        c4s[b] = *(const int4*)(col + base + idx4);
      }
    }
    // pass 1: LDS histogram + per-record rank; keep (bi,lrow5,rk) + col in regs
    unsigned pkv[20];                             // (bi<<13)|(lrow5<<8)|rk
    unsigned colp[10];                            // cols packed 2 per reg
#pragma unroll
    for (int b = 0; b < 5; ++b) {
      if (val[b]) {
        int rr[4] = {r4s[b].x, r4s[b].y, r4s[b].z, r4s[b].w};
        int cc[4] = {c4s[b].x, c4s[b].y, c4s[b].z, c4s[b].w};
#pragma unroll
        for (int j = 0; j < 4; ++j) {
          int bi = rr[j] >> 5;
          int rk = atomicAdd(&cnt[bi], 1);        // LDS atomic: cheap
          pkv[b * 4 + j] = ((unsigned)bi << 13) |
                           ((unsigned)(rr[j] & 31) << 8) | (unsigned)rk;
        }
        colp[b * 2]     = ((unsigned)cc[0] & 0xFFFFu) | ((unsigned)cc[1] << 16);
        colp[b * 2 + 1] = ((unsigned)cc[2] & 0xFFFFu) | ((unsigned)cc[3] << 16);
      } else {
#pragma unroll
        for (int j = 0; j < 4; ++j) pkv[b * 4 + j] = 0xFFFFFFFFu;
        colp[b * 2] = 0; colp[b * 2 + 1] = 0;
      }
    }
    __syncthreads();
    // in-block exclusive scan of cnt (chunks of 7, 256*7 >= NBINS)
    int c7[7];
    int s = 0;
#pragma unroll
    for (int k = 0; k < 7; ++k) {
      int i = tid * 7 + k;
      int c = (i < NBINS) ? cnt[i] : 0;
      c7[k] = c; s += c;
    }
    parts[tid] = s;
    __syncthreads();
    for (int off = 1; off < 256; off <<= 1) {     // Hillis-Steele inclusive
      int v = (tid >= off) ? parts[tid - off] : 0;
      __syncthreads();
      parts[tid] += v;
      __syncthreads();
    }
    int run = (tid > 0) ? parts[tid - 1] : 0;
    ushort* orow = obo + bid * OBW;
#pragma unroll
    for (int k = 0; k < 7; ++k) {
      int i = tid * 7 + k;
      if (i < NBINS) {
        orow[i] = (ushort)run;
        cnt[i] = run;                             // cnt becomes offset
        run += c7[k];
      }
    }
    if (tid == 0) orow[NBINS] = (ushort)EPB;
    __syncthreads();
    // pass 2: pure register -> LDS placement (no global reloads)
#pragma unroll
    for (int k = 0; k < 20; ++k) {
      unsigned p = pkv[k];
      if (p != 0xFFFFFFFFu) {
        int bi = (int)(p >> 13);
        int lr5 = (int)((p >> 8) & 31u);
        int rk = (int)(p & 255u);
        unsigned cw = (colp[k >> 1] >> ((k & 1) * 16)) & 0xFFFFu;
        recbuf[cnt[bi] + rk] = ((unsigned)lr5 << 16) | cw;
      }
    }
    __syncthreads();
    // coalesced dump: 1250 uint4
    uint4* gb4 = (uint4*)(binRec + base);
    const uint4* rb4 = (const uint4*)recbuf;
    for (int j = tid; j < EPB / 4; j += 256) gb4[j] = rb4[j];
  } else if (bid < FILLB + 3125) {
    int i = (bid - FILLB) * 256 + tid;            // 800000 threads exactly
    float4 a = x4[i * 2], b = x4[i * 2 + 1];
    uint4 o;
    o.x = pack2(a.x, a.y); o.y = pack2(a.z, a.w);
    o.z = pack2(b.x, b.y); o.w = pack2(b.z, b.w);
    xb4[i] = o;
  } else {
    for (int i = tid; i < 2048; i += 256) {
      float4 c = W4[i * 2], d = W4[i * 2 + 1];
      uint4 w;
      w.x = pack2(c.x, c.y); w.y = pack2(c.z, c.w);
      w.z = pack2(d.x, d.y); w.w = pack2(d.z, d.w);
      Wb4[i] = w;
    }
  }
}

// Fused Stage A (128 dense record runs -> per-row LDS lists) + Stage B
// (gather+normalize+residual, 8-wide unrolled) + GEMM (swapped-operand MFMA,
// hT XOR-swizzled). 256 threads = 4 waves per 32-row tile.
__global__ __launch_bounds__(256) void fused(const uint4* __restrict__ xb4,
                                             const unsigned* __restrict__ binRec,
                                             const ushort* __restrict__ obo,
                                             const uint4* __restrict__ Wb4,
                                             const float4* __restrict__ bias4,
                                             float4* __restrict__ out4) {
  __shared__ ushort hT[32 * CH];                   // 8192 B, slot s at s^(r&15)
  __shared__ __align__(16) ushort colL[32 * CAPR]; // 3072 B
  __shared__ int rowcnt[32];
  int tid = threadIdx.x;
  int g = blockIdx.x;
  int m0 = g * 32;

  // ---- Stage A: walk 128 dense runs (2 threads per run) ----
  if (tid < 32) rowcnt[tid] = 0;
  __syncthreads();
  {
    int i = tid >> 1, sub = tid & 1;
    const ushort* orow = obo + i * OBW + g;
    int o0 = orow[0], o1 = orow[1];
    const unsigned* rbase = binRec + i * EPB;
    for (int p = o0 + sub; p < o1; p += 2) {
      unsigned rec = __builtin_nontemporal_load(rbase + p);
      int lr = (int)(rec >> 16);
      int pp = atomicAdd(&rowcnt[lr], 1);
      if (pp < CAPR) colL[lr * CAPR + pp] = (ushort)(rec & 0xFFFFu);
    }
  }
  __syncthreads();

  // ---- Stage B: gather + normalize + residual -> hT (bf16) ----
  int wv = tid >> 6;          // 0..3
  int lane = tid & 63;
  int q = lane & 15;          // uint4 chunk within a 128-ch bf16 row
  int grp = lane >> 4;        // 0..3
#pragma unroll
  for (int t = 0; t < 2; ++t) {
    int r = wv * 8 + t * 4 + grp;
    int node = m0 + r;
    int deg = rowcnt[r];
    int degc = deg < CAPR ? deg : CAPR;
    const ushort* arow = colL + r * CAPR;
    int nc = node < N_NODES ? node : 0;
    uint4 xi = xb4[nc * 16 + q];         // residual, issued before the loop
    float acc[8] = {0.f, 0.f, 0.f, 0.f, 0.f, 0.f, 0.f, 0.f};
    int e = 0;
    for (; e + 7 < degc; e += 8) {       // 8 independent loads in flight
      uint4 ids = *(const uint4*)(arow + e);
      int n0 = ids.x & 0xFFFF, n1 = ids.x >> 16;
      int n2 = ids.y & 0xFFFF, n3 = ids.y >> 16;
      int n4 = ids.z & 0xFFFF, n5 = ids.z >> 16;
      int n6 = ids.w & 0xFFFF, n7 = ids.w >> 16;
      uint4 v0 = xb4[n0 * 16 + q];
      uint4 v1 = xb4[n1 * 16 + q];
      uint4 v2 = xb4[n2 * 16 + q];
      uint4 v3 = xb4[n3 * 16 + q];
      uint4 v4 = xb4[n4 * 16 + q];
      uint4 v5 = xb4[n5 * 16 + q];
      uint4 v6 = xb4[n6 * 16 + q];
      uint4 v7 = xb4[n7 * 16 + q];
      addrow(acc, v0); addrow(acc, v1); addrow(acc, v2); addrow(acc, v3);
      addrow(acc, v4); addrow(acc, v5); addrow(acc, v6); addrow(acc, v7);
    }
    if (e + 3 < degc) {
      uint2 ids = *(const uint2*)(arow + e);
      int n0 = ids.x & 0xFFFF, n1 = ids.x >> 16;
      int n2 = ids.y & 0xFFFF, n3 = ids.y >> 16;
      uint4 v0 = xb4[n0 * 16 + q];
      uint4 v1 = xb4[n1 * 16 + q];
      uint4 v2 = xb4[n2 * 16 + q];
      uint4 v3 = xb4[n3 * 16 + q];
      addrow(acc, v0); addrow(acc, v1); addrow(acc, v2); addrow(acc, v3);
      e += 4;
    }
    for (; e < degc; ++e) {
      uint4 v = xb4[(int)arow[e] * 16 + q];
      addrow(acc, v);
    }
    uint4 o = make_uint4(0, 0, 0, 0);
    if (node < N_NODES) {
      float s = 1.0f / fmaxf((float)deg, 1.0f);
      o.x = pack2(bflo(xi.x) + acc[0] * s, bfhi(xi.x) + acc[1] * s);
      o.y = pack2(bflo(xi.y) + acc[2] * s, bfhi(xi.y) + acc[3] * s);
      o.z = pack2(bflo(xi.z) + acc[4] * s, bfhi(xi.z) + acc[5] * s);
      o.w = pack2(bflo(xi.w) + acc[6] * s, bfhi(xi.w) + acc[7] * s);
    }
    *(uint4*)&hT[r * CH + ((q ^ (r & 15)) << 3)] = o;
  }
  __syncthreads();

  // ---- GEMM: swapped-operand MFMA, D[n=qq*4+r][m=lane&15] -> float4 stores
  // 2 m-tiles x 8 n-tiles over 4 waves: wv -> mt = wv&1, n-tiles (wv>>1)*4..+3
  // hT uint4-slot s of row r lives at s^(r&15): conflict-free fragment reads.
  int qq = grp;
  int mt = wv & 1;
  int nbase = (wv >> 1) * 4;
  const ushort* hbase = &hT[(mt * 16 + q) * CH];   // row rr_: rr_&15 == q
  bf16x8 hb0 = *(const bf16x8*)(hbase + (((qq + 0) ^ q) << 3));
  bf16x8 hb1 = *(const bf16x8*)(hbase + (((qq + 4) ^ q) << 3));
  bf16x8 hb2 = *(const bf16x8*)(hbase + (((qq + 8) ^ q) << 3));
  bf16x8 hb3 = *(const bf16x8*)(hbase + (((qq + 12) ^ q) << 3));
  int m = m0 + mt * 16 + q;
#pragma unroll
  for (int i = 0; i < 4; ++i) {
    int nt = nbase + i;
    const uint4* wr = Wb4 + (nt * 16 + q) * 16 + qq;   // k-step 32 bf16 = 4 uint4
    bf16x8 w0 = __builtin_bit_cast(bf16x8, wr[0]);
    bf16x8 w1 = __builtin_bit_cast(bf16x8, wr[4]);
    bf16x8 w2 = __builtin_bit_cast(bf16x8, wr[8]);
    bf16x8 w3 = __builtin_bit_cast(bf16x8, wr[12]);
    f32x4 acc = {0.f, 0.f, 0.f, 0.f};
    acc = __builtin_amdgcn_mfma_f32_16x16x32_bf16(w0, hb0, acc, 0, 0, 0);
    acc = __builtin_amdgcn_mfma_f32_16x16x32_bf16(w1, hb1, acc, 0, 0, 0);
    acc = __builtin_amdgcn_mfma_f32_16x16x32_bf16(w2, hb2, acc, 0, 0, 0);
    acc = __builtin_amdgcn_mfma_f32_16x16x32_bf16(w3, hb3, acc, 0, 0, 0);
    if (m < N_NODES) {
      float4 bv = bias4[nt * 4 + qq];
      f32x4 o;
      o.x = acc[0] + bv.x;
      o.y = acc[1] + bv.y;
      o.z = acc[2] + bv.z;
      o.w = acc[3] + bv.w;
      __builtin_nontemporal_store(o, (f32x4*)(out4 + (size_t)m * 32 + nt * 4 + qq));
    }
  }
}

extern "C" void kernel_launch(void* const* d_in, const int* in_sizes, int n_in,
                              void* d_out, int out_size, void* d_ws, size_t ws_size,
                              hipStream_t stream) {
  const float* x  = (const float*)d_in[0];
  const int*   ei = (const int*)d_in[1];    // [2, N_EDGES]: row then col
  const float* W  = (const float*)d_in[2];
  const float* bb = (const float*)d_in[3];

  char* ws = (char*)d_ws;
  unsigned* binRec = (unsigned*)ws;
  ushort*   obo    = (ushort*)(ws + 2560000);
  uint4*    Wb4    = (uint4*)(ws + 2960384);
  uint4*    xb4    = (uint4*)(ws + 2993152);

  fill_conv<<<FILLB + 3125 + 1, 256, 0, stream>>>(ei, ei + N_EDGES, binRec, obo,
                                                  (const float4*)x, xb4,
                                                  (const float4*)W, Wb4);
  fused<<<NTILES, 256, 0, stream>>>(xb4, binRec, obo, Wb4,
                                    (const float4*)bb, (float4*)d_out);
}